// Round 4
// baseline (163.093 us; speedup 1.0000x reference)
//
#include <hip/hip_runtime.h>
#include <hip/hip_bf16.h>
#include <math.h>

#define Mm 400
#define Cc 8
#define Ww 100
#define Dd 300
#define Hh 100
#define Rr 25
#define MC 3200   // M*C
#define KP 320    // K padded to multiple of 32
#define LBP_ITERS 5

typedef _Float16 f16x8 __attribute__((ext_vector_type(8)));
typedef _Float16 f16x4 __attribute__((ext_vector_type(4)));
typedef _Float16 f16x2 __attribute__((ext_vector_type(2)));
typedef float f32x4 __attribute__((ext_vector_type(4)));

__device__ __forceinline__ void gload16(const void* g, void* l) {
  __builtin_amdgcn_global_load_lds(
      (const __attribute__((address_space(1))) void*)g,
      (__attribute__((address_space(3))) void*)l, 16, 0, 0);
}

// ---------------------------------------------------------------------------
// Kernel 1: entity-context attention -> scores[m][c]; seeds col0 = scores.
// One block per mention. ctxt[m] staged ONCE as fp16 in LDS (XOR-swizzled),
// u-phase via MFMA, top-k in one wave's registers, ctxt_full from LDS.
// ---------------------------------------------------------------------------
__global__ __launch_bounds__(256) void k_entity_context(
    const float* __restrict__ ctxt_vec,   // [M][W][D]
    const float* __restrict__ cand_vec,   // [M][C][D]
    const float* __restrict__ A,          // [D]
    const float* __restrict__ B,          // [D]
    float* __restrict__ scores,           // [M*C]
    float* __restrict__ col0)             // [M*C]
{
  const int m = blockIdx.x;
  const int tid = threadIdx.x;
  __shared__ __align__(16) _Float16 ctxtH[112 * 320];  // 71,680 B (swizzled)
  __shared__ __align__(16) _Float16 candH[16 * 320];   // 10,240 B (swizzled)
  __shared__ float u_sh[112];
  __shared__ float beta_s[112];
  __shared__ float cfB[300];

  // zero both LDS tiles (k-pads / row-pads must be 0 — avoid NaN poisoning)
  {
    f16x8 z = {};
    for (int e = tid; e < 112 * 320 / 8; e += 256) *(f16x8*)&ctxtH[e * 8] = z;
    for (int e = tid; e < 16 * 320 / 8; e += 256) *(f16x8*)&candH[e * 8] = z;
  }
  __syncthreads();

  // stage ctxt rows fp32->fp16 (coalesced float4 reads), XOR-swizzled LDS
  const float* cw = ctxt_vec + (size_t)m * Ww * Dd;
  for (int e = tid; e < Ww * Dd / 4; e += 256) {      // 7500 float4
    int w = e / 75, j = e - w * 75;
    float4 v = *(const float4*)(cw + (size_t)e * 4);
    f16x4 h = { (_Float16)v.x, (_Float16)v.y, (_Float16)v.z, (_Float16)v.w };
    int byte = (w * 640 + j * 8) ^ ((w & 7) << 4);
    *(f16x4*)((char*)ctxtH + byte) = h;
  }
  // stage cand rows * A_linear
  const float* cev = cand_vec + (size_t)m * Cc * Dd;
  for (int e = tid; e < Cc * Dd / 4; e += 256) {      // 600 float4
    int c = e / 75, j = e - c * 75;
    float4 v = *(const float4*)(cev + (size_t)e * 4);
    float4 a = *(const float4*)(A + j * 4);
    f16x4 h = { (_Float16)(v.x * a.x), (_Float16)(v.y * a.y),
                (_Float16)(v.z * a.z), (_Float16)(v.w * a.w) };
    int byte = (c * 640 + j * 8) ^ ((c & 7) << 4);
    *(f16x4*)((char*)candH + byte) = h;
  }
  __syncthreads();

  // ---- u-phase: u[w] = max_c <A*e_c, ctxt_w> via 16x16x32 f16 MFMA ----
  const int wv = tid >> 6, lane = tid & 63;
  const int fr = lane & 15, fq = lane >> 4;
  {
    f32x4 acc0 = {}, acc1 = {};
    const bool has2 = (wv + 4) < 7;                    // 7 w-tiles of 16
    const int r0i = wv * 16 + fr, r1i = (wv + 4) * 16 + fr;
#pragma unroll
    for (int ks = 0; ks < 10; ++ks) {
      int k2 = ks * 64 + fq * 16;                      // byte offset of k-slice
      f16x8 af = *(const f16x8*)((const char*)candH + ((fr * 640 + k2) ^ ((fr & 7) << 4)));
      f16x8 bf0 = *(const f16x8*)((const char*)ctxtH + ((r0i * 640 + k2) ^ ((r0i & 7) << 4)));
      acc0 = __builtin_amdgcn_mfma_f32_16x16x32_f16(af, bf0, acc0, 0, 0, 0);
      if (has2) {
        f16x8 bf1 = *(const f16x8*)((const char*)ctxtH + ((r1i * 640 + k2) ^ ((r1i & 7) << 4)));
        acc1 = __builtin_amdgcn_mfma_f32_16x16x32_f16(af, bf1, acc1, 0, 0, 0);
      }
    }
    // D layout: col(w)=lane&15, row(c)=fq*4+r. Real c are rows 0..7 (fq<2).
    float v0 = fmaxf(fmaxf(acc0[0], acc0[1]), fmaxf(acc0[2], acc0[3]));
    if (fq >= 2) v0 = -1e30f;
    v0 = fmaxf(v0, __shfl_xor(v0, 16));
    if (fq == 0 && r0i < Ww) u_sh[r0i] = v0;
    if (has2) {
      float v1 = fmaxf(fmaxf(acc1[0], acc1[1]), fmaxf(acc1[2], acc1[3]));
      if (fq >= 2) v1 = -1e30f;
      v1 = fmaxf(v1, __shfl_xor(v1, 16));
      if (fq == 0 && r1i < Ww) u_sh[r1i] = v1;
    }
  }
  __syncthreads();

  // ---- top-k (25th largest w/ multiplicity) + softmax, all in wave 0 ----
  if (tid < 64) {
    float a0 = u_sh[tid];
    float a1 = (tid + 64 < Ww) ? u_sh[tid + 64] : -1e30f;
    float r0 = a0, r1 = a1, sketch = 0.f;
    for (int r = 0; r < Rr; ++r) {
      float v; int idx;
      if (r1 > r0) { v = r1; idx = tid + 64; } else { v = r0; idx = tid; }
#pragma unroll
      for (int off = 1; off < 64; off <<= 1) {
        float ov = __shfl_xor(v, off);
        int   oi = __shfl_xor(idx, off);
        if (ov > v || (ov == v && oi < idx)) { v = ov; idx = oi; }  // deterministic winner
      }
      sketch = v;
      if (idx == tid) r0 = -1e30f;
      else if (idx == tid + 64) r1 = -1e30f;
    }
    // Threshold(0,-50) + softmax over the 100 u values
    float m0 = (a0 > sketch) ? a0 : sketch - 50.0f;
    float m1 = (tid + 64 < Ww) ? ((a1 > sketch) ? a1 : sketch - 50.0f) : -1e30f;
    float mx = fmaxf(m0, m1);
#pragma unroll
    for (int off = 1; off < 64; off <<= 1) mx = fmaxf(mx, __shfl_xor(mx, off));
    float e0 = expf(m0 - mx);
    float e1 = (tid + 64 < Ww) ? expf(m1 - mx) : 0.f;
    float s = e0 + e1;
#pragma unroll
    for (int off = 1; off < 64; off <<= 1) s += __shfl_xor(s, off);
    float inv = 1.0f / s;
    beta_s[tid] = e0 * inv;
    if (tid + 64 < Ww) beta_s[tid + 64] = e1 * inv;
  }
  __syncthreads();

  // ---- ctxt_full*B from LDS fp16 copy (no global re-read) ----
  if (tid < 150) {
    float c0 = 0.f, c1 = 0.f;
    for (int w = 0; w < Ww; ++w) {
      int byte = (w * 640 + tid * 4) ^ ((w & 7) << 4);
      f16x2 h = *(const f16x2*)((const char*)ctxtH + byte);
      float bw = beta_s[w];
      c0 += bw * (float)h[0];
      c1 += bw * (float)h[1];
    }
    float2 b2v = *(const float2*)(B + 2 * tid);
    cfB[2 * tid]     = c0 * b2v.x;
    cfB[2 * tid + 1] = c1 * b2v.y;
  }
  __syncthreads();

  // ---- scores[m][c] = <e_c, cfB> (cand rows are L2-hot) ----
  if (tid < 128) {
    int c = tid >> 4, ln = tid & 15;
    float p = 0.f;
    for (int d = ln; d < Dd; d += 16) p += cev[c * Dd + d] * cfB[d];
#pragma unroll
    for (int off = 8; off; off >>= 1) p += __shfl_down(p, off, 16);
    if (ln == 0) { scores[m * Cc + c] = p; col0[m * Cc + c] = p; }
  }
}

// ---------------------------------------------------------------------------
// fp16 conversion: Ah = fp16(X*Cl), Bh = fp16(X), K padded 300->320 w/ zeros
// ---------------------------------------------------------------------------
__global__ __launch_bounds__(256) void k_convert(
    const float* __restrict__ X,   // [MC][D]
    const float* __restrict__ Cl,  // [D]
    _Float16* __restrict__ Ah,     // [MC][KP]
    _Float16* __restrict__ Bh)     // [MC][KP]
{
  int idx = blockIdx.x * 256 + threadIdx.x;
  if (idx >= MC * KP) return;
  int j = idx / KP, k = idx - j * KP;
  float x = 0.f, cl = 0.f;
  if (k < Dd) { x = X[(size_t)j * Dd + k]; cl = Cl[k]; }
  Bh[idx] = (_Float16)x;
  Ah[idx] = (_Float16)(x * cl);
}

// ---------------------------------------------------------------------------
// Kernel 2: P = Ah @ Bh^T  [3200 x 3200], K=320, fp16 MFMA, fp32 accum,
// fp16 output via LDS-staged coalesced epilogue.
// ---------------------------------------------------------------------------
__global__ __launch_bounds__(256) void k_pairwise_mfma(
    const _Float16* __restrict__ Ah,  // [MC][KP]
    const _Float16* __restrict__ Bh,  // [MC][KP]
    _Float16* __restrict__ P)         // [MC][MC] fp16
{
  __shared__ __align__(16) _Float16 Sh[2][128 * 32];  // As = Sh[0], Bs = Sh[1]
  const int tid = threadIdx.x;
  const int wave = tid >> 6, lane = tid & 63;
  const int wr = wave >> 1, wc = wave & 1;            // 2x2 wave grid
  const int row0 = blockIdx.y * 128, col0 = blockIdx.x * 128;

  f32x4 acc[4][4] = {};
  const int fr = lane & 15, fq = lane >> 4;
  const int koff = fq * 8;

  for (int kt = 0; kt < KP / 32; ++kt) {
    const int k0 = kt * 32;
#pragma unroll
    for (int i = 0; i < 2; ++i) {
      int e = i * 256 + tid;
      int r = e >> 2;
      int kc = (e & 3) << 3;
      gload16(Ah + (size_t)(row0 + r) * KP + k0 + kc, (char*)Sh[0] + e * 16);
      gload16(Bh + (size_t)(col0 + r) * KP + k0 + kc, (char*)Sh[1] + e * 16);
    }
    __syncthreads();

    f16x8 af[4], bfr[4];
#pragma unroll
    for (int mi = 0; mi < 4; ++mi)
      af[mi] = *(const f16x8*)&Sh[0][(wr * 64 + mi * 16 + fr) * 32 + koff];
#pragma unroll
    for (int ni = 0; ni < 4; ++ni)
      bfr[ni] = *(const f16x8*)&Sh[1][(wc * 64 + ni * 16 + fr) * 32 + koff];
#pragma unroll
    for (int mi = 0; mi < 4; ++mi)
#pragma unroll
      for (int ni = 0; ni < 4; ++ni)
        acc[mi][ni] = __builtin_amdgcn_mfma_f32_16x16x32_f16(
            af[mi], bfr[ni], acc[mi][ni], 0, 0, 0);
    __syncthreads();
  }

  // epilogue: acc -> fp16 via per-wave 4KB LDS tile, coalesced 16B stores.
  // Two halves of 32 rows each (4 waves x 4KB = 16KB = all of Sh).
  _Float16* wtile = (_Float16*)((char*)Sh + wave * 4096);
#pragma unroll
  for (int h = 0; h < 2; ++h) {
    __syncthreads();
#pragma unroll
    for (int mi2 = 0; mi2 < 2; ++mi2) {
      int mi = h * 2 + mi2;
#pragma unroll
      for (int ni = 0; ni < 4; ++ni)
#pragma unroll
        for (int r = 0; r < 4; ++r)
          wtile[(mi2 * 16 + fq * 4 + r) * 64 + ni * 16 + fr] =
              (_Float16)acc[mi][ni][r];
    }
    __syncthreads();
#pragma unroll
    for (int t = 0; t < 4; ++t) {
      int q = t * 64 + lane;
      int lr = q >> 3, lc8 = (q & 7) * 8;
      f16x8 v = *(const f16x8*)&wtile[lr * 64 + lc8];
      size_t gr = (size_t)(row0 + wr * 64 + h * 32 + lr);
      size_t gc = (size_t)(col0 + wc * 64 + lc8);
      *(f16x8*)(P + gr * MC + gc) = v;
    }
  }
}

// ---------------------------------------------------------------------------
// LBP step (fused col production), fp16 P reads
// ---------------------------------------------------------------------------
__global__ __launch_bounds__(256) void k_lbp(
    const _Float16* __restrict__ P,
    const float* __restrict__ colIn,
    const float* __restrict__ scores,
    float* __restrict__ msg,
    float* __restrict__ colOut)
{
  const int aa = blockIdx.x;
  __shared__ __align__(16) float col_s[MC];
  __shared__ float red_s[4][Cc];
  for (int i = threadIdx.x; i < MC; i += 256) col_s[i] = colIn[i];
  __syncthreads();

  float psum[Cc];
#pragma unroll
  for (int b = 0; b < Cc; ++b) psum[b] = 0.f;

  for (int m = threadIdx.x; m < Mm; m += 256) {
    const float4 c0 = *reinterpret_cast<const float4*>(&col_s[m * 8]);
    const float4 c1 = *reinterpret_cast<const float4*>(&col_s[m * 8 + 4]);
    float t[Cc];
#pragma unroll
    for (int b = 0; b < Cc; ++b) {
      f16x8 ph = *(const f16x8*)(P + (size_t)(aa * 8 + b) * MC + m * 8);
      float tb = fmaxf(fmaxf((float)ph[0] + c0.x, (float)ph[1] + c0.y),
                       fmaxf((float)ph[2] + c0.z, (float)ph[3] + c0.w));
      t[b] = fmaxf(tb, fmaxf(fmaxf((float)ph[4] + c1.x, (float)ph[5] + c1.y),
                             fmaxf((float)ph[6] + c1.z, (float)ph[7] + c1.w)));
    }
    float mxt = t[0];
#pragma unroll
    for (int b = 1; b < Cc; ++b) mxt = fmaxf(mxt, t[b]);
    float se = 0.f;
#pragma unroll
    for (int b = 0; b < Cc; ++b) se += expf(t[b] - mxt);
    float lse = mxt + logf(se);
    bool self = (m == aa);
#pragma unroll
    for (int b = 0; b < Cc; ++b) {
      float sel = self ? 0.f : (t[b] - lse);
      size_t mi = (size_t)(aa * 8 + b) * Mm + m;
      float old = msg[mi];
      float nv = logf(0.5f * expf(sel) + 0.5f * expf(old));
      msg[mi] = nv;
      psum[b] += nv;
    }
  }

  const int wave = threadIdx.x >> 6, lane = threadIdx.x & 63;
#pragma unroll
  for (int b = 0; b < Cc; ++b)
#pragma unroll
    for (int off = 32; off; off >>= 1) psum[b] += __shfl_down(psum[b], off);
  if (lane == 0)
#pragma unroll
    for (int b = 0; b < Cc; ++b) red_s[wave][b] = psum[b];
  __syncthreads();
  if (threadIdx.x < Cc) {
    int b = threadIdx.x;
    float s = red_s[0][b] + red_s[1][b] + red_s[2][b] + red_s[3][b];
    colOut[aa * Cc + b] = scores[aa * Cc + b] + s;
  }
}

// ---------------------------------------------------------------------------
// Final: fgs = log_softmax(colF, axis=C); tiny MLP. One thread per mention.
// ---------------------------------------------------------------------------
__global__ __launch_bounds__(64) void k_final2(
    const float* __restrict__ colF,    // [MC] = scores + global_message
    const float* __restrict__ pem,     // [MC]
    const float* __restrict__ W1,      // [H][2]
    const float* __restrict__ b1,      // [H]
    const float* __restrict__ W2,      // [H]
    const float* __restrict__ b2,      // [1]
    float* __restrict__ out)           // [MC]
{
  int m = blockIdx.x * 64 + threadIdx.x;
  if (m >= Mm) return;
  float f[Cc], pm[Cc];
#pragma unroll
  for (int c = 0; c < Cc; ++c) {
    f[c] = colF[m * Cc + c];
    pm[c] = pem[m * Cc + c];
  }
  float mx = f[0];
#pragma unroll
  for (int c = 1; c < Cc; ++c) mx = fmaxf(mx, f[c]);
  float se = 0.f;
#pragma unroll
  for (int c = 0; c < Cc; ++c) se += expf(f[c] - mx);
  float lse = mx + logf(se);
  float fgs[Cc], accv[Cc];
  float bb2 = b2[0];
#pragma unroll
  for (int c = 0; c < Cc; ++c) { fgs[c] = f[c] - lse; accv[c] = bb2; }
  for (int h = 0; h < Hh; ++h) {
    float w0 = W1[2 * h], w1 = W1[2 * h + 1], bb = b1[h], w2 = W2[h];
#pragma unroll
    for (int c = 0; c < Cc; ++c)
      accv[c] += w2 * fmaxf(fgs[c] * w0 + pm[c] * w1 + bb, 0.f);
  }
#pragma unroll
  for (int c = 0; c < Cc; ++c) out[m * Cc + c] = accv[c];
}

// ---------------------------------------------------------------------------
extern "C" void kernel_launch(void* const* d_in, const int* in_sizes, int n_in,
                              void* d_out, int out_size, void* d_ws, size_t ws_size,
                              hipStream_t stream) {
  const float* ctxt_vec = (const float*)d_in[1];   // [M][W][D]
  const float* cand_vec = (const float*)d_in[3];   // [M][C][D]
  const float* pem      = (const float*)d_in[4];   // [M][C]
  const float* A        = (const float*)d_in[5];
  const float* B        = (const float*)d_in[6];
  const float* Cl       = (const float*)d_in[7];
  const float* W1       = (const float*)d_in[8];
  const float* b1       = (const float*)d_in[9];
  const float* W2       = (const float*)d_in[10];
  const float* b2       = (const float*)d_in[11];
  float* out = (float*)d_out;

  char* ws = (char*)d_ws;
  _Float16* P     = (_Float16*)(ws);                      // 20,480,000 B
  float*   msg    = (float*)(ws + 20480000);              //  5,120,000 B
  // Ah/Bh alias the msg region (live only until GEMM; memset is after GEMM)
  _Float16* Ah    = (_Float16*)(ws + 20480000);           //  2,048,000 B
  _Float16* Bh    = (_Float16*)(ws + 20480000 + 2048000); //  2,048,000 B
  float*   scores = (float*)(ws + 25600000);
  float*   col0   = scores + MC;
  float*   col1   = col0 + MC;

  k_convert<<<(MC * KP + 255) / 256, 256, 0, stream>>>(cand_vec, Cl, Ah, Bh);
  k_entity_context<<<Mm, 256, 0, stream>>>(ctxt_vec, cand_vec, A, B, scores, col0);

  dim3 g(MC / 128, MC / 128);
  k_pairwise_mfma<<<g, 256, 0, stream>>>(Ah, Bh, P);

  hipMemsetAsync(msg, 0, (size_t)MC * Mm * sizeof(float), stream);  // after GEMM (alias!)

  float* cIn = col0; float* cOut = col1;
  for (int it = 0; it < LBP_ITERS; ++it) {
    k_lbp<<<Mm, 256, 0, stream>>>(P, cIn, scores, msg, cOut);
    float* t = cIn; cIn = cOut; cOut = t;
  }
  k_final2<<<(Mm + 63) / 64, 64, 0, stream>>>(cIn, pem, W1, b1, W2, b2, out);
}

// Round 6
// 145.121 us; speedup vs baseline: 1.1238x; 1.1238x over previous
//
#include <hip/hip_runtime.h>
#include <hip/hip_bf16.h>
#include <math.h>

#define Mm 400
#define Cc 8
#define Ww 100
#define Dd 300
#define Hh 100
#define Rr 25
#define MC 3200   // M*C
#define KP 320    // K padded to multiple of 32
#define LBP_ITERS 5

typedef _Float16 f16x8 __attribute__((ext_vector_type(8)));
typedef _Float16 f16x4 __attribute__((ext_vector_type(4)));
typedef _Float16 f16x2 __attribute__((ext_vector_type(2)));
typedef float f32x4 __attribute__((ext_vector_type(4)));

__device__ __forceinline__ void gload16(const void* g, void* l) {
  __builtin_amdgcn_global_load_lds(
      (const __attribute__((address_space(1))) void*)g,
      (__attribute__((address_space(3))) void*)l, 16, 0, 0);
}

// ---------------------------------------------------------------------------
// Kernel 1: entity-context attention -> scores[m][c]; seeds col0 = scores.
// One block per mention, 256 threads. LDS ~52KB -> 3 blocks/CU.
// u-phase: fp16 MFMA over two k=160 chunks (acc in regs across chunks).
// NOTE: all k-pad regions MUST be zeroed (k-dim is summed by MFMA). The
// fills below are stride-256 loops — a 256-thread block cannot cover >256
// items with a bare `if (tid < N)` (round-5 bug).
// ---------------------------------------------------------------------------
__global__ __launch_bounds__(256) void k_entity_context(
    const float* __restrict__ ctxt_vec,   // [M][W][D]
    const float* __restrict__ cand_vec,   // [M][C][D]
    const float* __restrict__ A,          // [D]
    const float* __restrict__ B,          // [D]
    float* __restrict__ scores,           // [M*C]
    float* __restrict__ col0)             // [M*C]
{
  const int m = blockIdx.x;
  const int tid = threadIdx.x;
  __shared__ __align__(16) _Float16 ctxtC[112 * 160];  // 35,840 B (one k-chunk)
  __shared__ __align__(16) _Float16 candH[16 * 320];   // 10,240 B (full K)
  __shared__ __align__(16) float cf_part[3 * 300];     //  3,600 B
  __shared__ __align__(16) float cfB[304];
  __shared__ float u_sh[Ww];
  __shared__ float beta_s[Ww];

  const float* cw  = ctxt_vec + (size_t)m * Ww * Dd;
  const float* cev = cand_vec + (size_t)m * Cc * Dd;

  // ---- Phase A: stage candH = fp16(cand * A), pads zeroed (disjoint writes)
  for (int e = tid; e < Cc * 75; e += 256) {            // 600 float4
    int c = e / 75, j = e - c * 75;
    float4 v = *(const float4*)(cev + (size_t)e * 4);
    float4 a = *(const float4*)(A + j * 4);
    f16x4 h = { (_Float16)(v.x * a.x), (_Float16)(v.y * a.y),
                (_Float16)(v.z * a.z), (_Float16)(v.w * a.w) };
    *(f16x4*)((char*)candH + c * 640 + j * 8) = h;
  }
  // rows 8..15 zero (320 x 16B)
  for (int e = tid; e < 320; e += 256) {
    f16x8 z = {};
    *(f16x8*)((char*)candH + 5120 + e * 16) = z;
  }
  // rows 0..7 k-pad bytes 600..640 (40 x 8B) — k-dim pad, MUST be zero
  if (tid < 40) {
    int row = tid / 5, q = tid - row * 5;
    f16x4 z = {};
    *(f16x4*)((char*)candH + row * 640 + 600 + q * 8) = z;
  }
  // stage ctxt chunk0: d 0..159, rows 0..99 (40 float4/row)
  for (int e = tid; e < Ww * 40; e += 256) {
    int w = e / 40, j = e - w * 40;
    float4 v = *(const float4*)(cw + (size_t)w * Dd + j * 4);
    f16x4 h = { (_Float16)v.x, (_Float16)v.y, (_Float16)v.z, (_Float16)v.w };
    *(f16x4*)((char*)ctxtC + w * 320 + j * 8) = h;
  }
  __syncthreads();

  // ---- Phase B: MFMA u, chunk 0 (k-steps 0..4) ----
  const int wv = tid >> 6, lane = tid & 63;
  const int fr = lane & 15, fq = lane >> 4;
  const int t1 = wv + 4;
  const bool has2 = t1 < 7;                 // 7 w-tiles of 16
  const int r0 = wv * 16 + fr, r1 = t1 * 16 + fr;
  f32x4 acc0 = {}, acc1 = {};
#pragma unroll
  for (int s = 0; s < 5; ++s) {
    int kb  = s * 64 + fq * 16;
    f16x8 af = *(const f16x8*)((const char*)candH + fr * 640 + kb);
    f16x8 b0 = *(const f16x8*)((const char*)ctxtC + r0 * 320 + kb);
    acc0 = __builtin_amdgcn_mfma_f32_16x16x32_f16(af, b0, acc0, 0, 0, 0);
    if (has2) {
      f16x8 b1 = *(const f16x8*)((const char*)ctxtC + r1 * 320 + kb);
      acc1 = __builtin_amdgcn_mfma_f32_16x16x32_f16(af, b1, acc1, 0, 0, 0);
    }
  }
  __syncthreads();

  // ---- stage chunk1: d 160..299 (35 float4/row) + zero k-pad bytes 280..320
  for (int e = tid; e < Ww * 35; e += 256) {
    int w = e / 35, j = e - w * 35;
    float4 v = *(const float4*)(cw + (size_t)w * Dd + 160 + j * 4);
    f16x4 h = { (_Float16)v.x, (_Float16)v.y, (_Float16)v.z, (_Float16)v.w };
    *(f16x4*)((char*)ctxtC + w * 320 + j * 8) = h;
  }
  // k-pad rows 0..99, bytes 280..320 (500 x 8B) — k-dim pad, MUST be zero
  for (int e = tid; e < 500; e += 256) {
    int row = e / 5, q = e - row * 5;
    f16x4 z = {};
    *(f16x4*)((char*)ctxtC + row * 320 + 280 + q * 8) = z;
  }
  __syncthreads();

  // ---- Phase B2: MFMA u, chunk 1 (k-steps 5..9) ----
#pragma unroll
  for (int s = 0; s < 5; ++s) {
    int kb  = s * 64 + fq * 16;
    f16x8 af = *(const f16x8*)((const char*)candH + fr * 640 + 320 + kb);
    f16x8 b0 = *(const f16x8*)((const char*)ctxtC + r0 * 320 + kb);
    acc0 = __builtin_amdgcn_mfma_f32_16x16x32_f16(af, b0, acc0, 0, 0, 0);
    if (has2) {
      f16x8 b1 = *(const f16x8*)((const char*)ctxtC + r1 * 320 + kb);
      acc1 = __builtin_amdgcn_mfma_f32_16x16x32_f16(af, b1, acc1, 0, 0, 0);
    }
  }
  // D layout: col(w)=lane&15 (== r0/r1 row idx), row(c)=fq*4+reg; real c rows 0..7
  {
    float v0 = fmaxf(fmaxf(acc0[0], acc0[1]), fmaxf(acc0[2], acc0[3]));
    if (fq >= 2) v0 = -1e30f;
    v0 = fmaxf(v0, __shfl_xor(v0, 16));
    if (fq == 0 && r0 < Ww) u_sh[r0] = v0;
    if (has2) {
      float v1 = fmaxf(fmaxf(acc1[0], acc1[1]), fmaxf(acc1[2], acc1[3]));
      if (fq >= 2) v1 = -1e30f;
      v1 = fmaxf(v1, __shfl_xor(v1, 16));
      if (fq == 0 && r1 < Ww) u_sh[r1] = v1;
    }
  }
  __syncthreads();

  // ---- top-k (25th largest w/ multiplicity) + softmax, wave 0 in registers
  if (tid < 64) {
    float a0 = u_sh[tid];
    float a1 = (tid + 64 < Ww) ? u_sh[tid + 64] : -1e30f;
    float q0 = a0, q1 = a1, sketch = 0.f;
    for (int r = 0; r < Rr; ++r) {
      float v; int idx;
      if (q1 > q0) { v = q1; idx = tid + 64; } else { v = q0; idx = tid; }
#pragma unroll
      for (int off = 1; off < 64; off <<= 1) {
        float ov = __shfl_xor(v, off);
        int   oi = __shfl_xor(idx, off);
        if (ov > v || (ov == v && oi < idx)) { v = ov; idx = oi; }
      }
      sketch = v;
      if (idx == tid) q0 = -1e30f;
      else if (idx == tid + 64) q1 = -1e30f;
    }
    float m0 = (a0 > sketch) ? a0 : sketch - 50.0f;
    float m1 = (tid + 64 < Ww) ? ((a1 > sketch) ? a1 : sketch - 50.0f) : -1e30f;
    float mx = fmaxf(m0, m1);
#pragma unroll
    for (int off = 1; off < 64; off <<= 1) mx = fmaxf(mx, __shfl_xor(mx, off));
    float e0 = expf(m0 - mx);
    float e1 = (tid + 64 < Ww) ? expf(m1 - mx) : 0.f;
    float s = e0 + e1;
#pragma unroll
    for (int off = 1; off < 64; off <<= 1) s += __shfl_xor(s, off);
    float inv = 1.0f / s;
    beta_s[tid] = e0 * inv;
    if (tid + 64 < Ww) beta_s[tid + 64] = e1 * inv;
  }
  __syncthreads();

  // ---- ctxt_full partials: fp32 coalesced global re-read, 3 w-groups x 75 d4
  if (tid < 225) {
    int tg = tid / 75, d4 = tid - tg * 75;
    f32x4 cf = {};
    for (int w = tg; w < Ww; w += 3) {
      float4 x = *(const float4*)(cw + (size_t)w * Dd + d4 * 4);
      float bw = beta_s[w];
      cf[0] += bw * x.x; cf[1] += bw * x.y; cf[2] += bw * x.z; cf[3] += bw * x.w;
    }
    *(f32x4*)&cf_part[(tg * 75 + d4) * 4] = cf;
  }
  __syncthreads();

  // ---- combine partials, apply B ----
  if (tid < 75) {
    f32x4 s4 = *(const f32x4*)&cf_part[tid * 4];
    s4 += *(const f32x4*)&cf_part[(75 + tid) * 4];
    s4 += *(const f32x4*)&cf_part[(150 + tid) * 4];
    float4 b4 = *(const float4*)(B + tid * 4);
    s4[0] *= b4.x; s4[1] *= b4.y; s4[2] *= b4.z; s4[3] *= b4.w;
    *(f32x4*)&cfB[tid * 4] = s4;
  }
  __syncthreads();

  // ---- scores[m][c] = <e_c, cfB> ----
  if (tid < 128) {
    int c = tid >> 4, l = tid & 15;
    float p = 0.f;
    for (int d4 = l; d4 < 75; d4 += 16) {
      float4 x = *(const float4*)(cev + (size_t)c * Dd + d4 * 4);
      f32x4 f = *(const f32x4*)&cfB[d4 * 4];
      p += x.x * f[0] + x.y * f[1] + x.z * f[2] + x.w * f[3];
    }
#pragma unroll
    for (int off = 8; off; off >>= 1) p += __shfl_down(p, off, 16);
    if (l == 0) { scores[m * Cc + c] = p; col0[m * Cc + c] = p; }
  }
}

// ---------------------------------------------------------------------------
// fp16 conversion: Ah = fp16(X*Cl), Bh = fp16(X), K padded 300->320 w/ zeros
// ---------------------------------------------------------------------------
__global__ __launch_bounds__(256) void k_convert(
    const float* __restrict__ X,   // [MC][D]
    const float* __restrict__ Cl,  // [D]
    _Float16* __restrict__ Ah,     // [MC][KP]
    _Float16* __restrict__ Bh)     // [MC][KP]
{
  int idx = blockIdx.x * 256 + threadIdx.x;
  if (idx >= MC * KP) return;
  int j = idx / KP, k = idx - j * KP;
  float x = 0.f, cl = 0.f;
  if (k < Dd) { x = X[(size_t)j * Dd + k]; cl = Cl[k]; }
  Bh[idx] = (_Float16)x;
  Ah[idx] = (_Float16)(x * cl);
}

// ---------------------------------------------------------------------------
// Kernel 2: P = Ah @ Bh^T  [3200 x 3200], K=320, fp16 MFMA, fp32 accum,
// fp16 output via LDS-staged coalesced epilogue.
// ---------------------------------------------------------------------------
__global__ __launch_bounds__(256) void k_pairwise_mfma(
    const _Float16* __restrict__ Ah,  // [MC][KP]
    const _Float16* __restrict__ Bh,  // [MC][KP]
    _Float16* __restrict__ P)         // [MC][MC] fp16
{
  __shared__ __align__(16) _Float16 Sh[2][128 * 32];  // As = Sh[0], Bs = Sh[1]
  const int tid = threadIdx.x;
  const int wave = tid >> 6, lane = tid & 63;
  const int wr = wave >> 1, wc = wave & 1;            // 2x2 wave grid
  const int row0 = blockIdx.y * 128, col0 = blockIdx.x * 128;

  f32x4 acc[4][4] = {};
  const int fr = lane & 15, fq = lane >> 4;
  const int koff = fq * 8;

  for (int kt = 0; kt < KP / 32; ++kt) {
    const int k0 = kt * 32;
#pragma unroll
    for (int i = 0; i < 2; ++i) {
      int e = i * 256 + tid;
      int r = e >> 2;
      int kc = (e & 3) << 3;
      gload16(Ah + (size_t)(row0 + r) * KP + k0 + kc, (char*)Sh[0] + e * 16);
      gload16(Bh + (size_t)(col0 + r) * KP + k0 + kc, (char*)Sh[1] + e * 16);
    }
    __syncthreads();

    f16x8 af[4], bfr[4];
#pragma unroll
    for (int mi = 0; mi < 4; ++mi)
      af[mi] = *(const f16x8*)&Sh[0][(wr * 64 + mi * 16 + fr) * 32 + koff];
#pragma unroll
    for (int ni = 0; ni < 4; ++ni)
      bfr[ni] = *(const f16x8*)&Sh[1][(wc * 64 + ni * 16 + fr) * 32 + koff];
#pragma unroll
    for (int mi = 0; mi < 4; ++mi)
#pragma unroll
      for (int ni = 0; ni < 4; ++ni)
        acc[mi][ni] = __builtin_amdgcn_mfma_f32_16x16x32_f16(
            af[mi], bfr[ni], acc[mi][ni], 0, 0, 0);
    __syncthreads();
  }

  // epilogue: acc -> fp16 via per-wave 4KB LDS tile, coalesced 16B stores.
  _Float16* wtile = (_Float16*)((char*)Sh + wave * 4096);
#pragma unroll
  for (int h = 0; h < 2; ++h) {
    __syncthreads();
#pragma unroll
    for (int mi2 = 0; mi2 < 2; ++mi2) {
      int mi = h * 2 + mi2;
#pragma unroll
      for (int ni = 0; ni < 4; ++ni)
#pragma unroll
        for (int r = 0; r < 4; ++r)
          wtile[(mi2 * 16 + fq * 4 + r) * 64 + ni * 16 + fr] =
              (_Float16)acc[mi][ni][r];
    }
    __syncthreads();
#pragma unroll
    for (int t = 0; t < 4; ++t) {
      int q = t * 64 + lane;
      int lr = q >> 3, lc8 = (q & 7) * 8;
      f16x8 v = *(const f16x8*)&wtile[lr * 64 + lc8];
      size_t gr = (size_t)(row0 + wr * 64 + h * 32 + lr);
      size_t gc = (size_t)(col0 + wc * 64 + lc8);
      *(f16x8*)(P + gr * MC + gc) = v;
    }
  }
}

// ---------------------------------------------------------------------------
// LBP step (fused col production), fp16 P reads
// ---------------------------------------------------------------------------
__global__ __launch_bounds__(256) void k_lbp(
    const _Float16* __restrict__ P,
    const float* __restrict__ colIn,
    const float* __restrict__ scores,
    float* __restrict__ msg,
    float* __restrict__ colOut)
{
  const int aa = blockIdx.x;
  __shared__ __align__(16) float col_s[MC];
  __shared__ float red_s[4][Cc];
  for (int i = threadIdx.x; i < MC; i += 256) col_s[i] = colIn[i];
  __syncthreads();

  float psum[Cc];
#pragma unroll
  for (int b = 0; b < Cc; ++b) psum[b] = 0.f;

  for (int m = threadIdx.x; m < Mm; m += 256) {
    const float4 c0 = *reinterpret_cast<const float4*>(&col_s[m * 8]);
    const float4 c1 = *reinterpret_cast<const float4*>(&col_s[m * 8 + 4]);
    float t[Cc];
#pragma unroll
    for (int b = 0; b < Cc; ++b) {
      f16x8 ph = *(const f16x8*)(P + (size_t)(aa * 8 + b) * MC + m * 8);
      float tb = fmaxf(fmaxf((float)ph[0] + c0.x, (float)ph[1] + c0.y),
                       fmaxf((float)ph[2] + c0.z, (float)ph[3] + c0.w));
      t[b] = fmaxf(tb, fmaxf(fmaxf((float)ph[4] + c1.x, (float)ph[5] + c1.y),
                             fmaxf((float)ph[6] + c1.z, (float)ph[7] + c1.w)));
    }
    float mxt = t[0];
#pragma unroll
    for (int b = 1; b < Cc; ++b) mxt = fmaxf(mxt, t[b]);
    float se = 0.f;
#pragma unroll
    for (int b = 0; b < Cc; ++b) se += expf(t[b] - mxt);
    float lse = mxt + logf(se);
    bool self = (m == aa);
#pragma unroll
    for (int b = 0; b < Cc; ++b) {
      float sel = self ? 0.f : (t[b] - lse);
      size_t mi = (size_t)(aa * 8 + b) * Mm + m;
      float old = msg[mi];
      float nv = logf(0.5f * expf(sel) + 0.5f * expf(old));
      msg[mi] = nv;
      psum[b] += nv;
    }
  }

  const int wave = threadIdx.x >> 6, lane = threadIdx.x & 63;
#pragma unroll
  for (int b = 0; b < Cc; ++b)
#pragma unroll
    for (int off = 32; off; off >>= 1) psum[b] += __shfl_down(psum[b], off);
  if (lane == 0)
#pragma unroll
    for (int b = 0; b < Cc; ++b) red_s[wave][b] = psum[b];
  __syncthreads();
  if (threadIdx.x < Cc) {
    int b = threadIdx.x;
    float s = red_s[0][b] + red_s[1][b] + red_s[2][b] + red_s[3][b];
    colOut[aa * Cc + b] = scores[aa * Cc + b] + s;
  }
}

// ---------------------------------------------------------------------------
// Final: fgs = log_softmax(colF, axis=C); tiny MLP. One thread per mention.
// ---------------------------------------------------------------------------
__global__ __launch_bounds__(64) void k_final2(
    const float* __restrict__ colF,    // [MC] = scores + global_message
    const float* __restrict__ pem,     // [MC]
    const float* __restrict__ W1,      // [H][2]
    const float* __restrict__ b1,      // [H]
    const float* __restrict__ W2,      // [H]
    const float* __restrict__ b2,      // [1]
    float* __restrict__ out)           // [MC]
{
  int m = blockIdx.x * 64 + threadIdx.x;
  if (m >= Mm) return;
  float f[Cc], pm[Cc];
#pragma unroll
  for (int c = 0; c < Cc; ++c) {
    f[c] = colF[m * Cc + c];
    pm[c] = pem[m * Cc + c];
  }
  float mx = f[0];
#pragma unroll
  for (int c = 1; c < Cc; ++c) mx = fmaxf(mx, f[c]);
  float se = 0.f;
#pragma unroll
  for (int c = 0; c < Cc; ++c) se += expf(f[c] - mx);
  float lse = mx + logf(se);
  float fgs[Cc], accv[Cc];
  float bb2 = b2[0];
#pragma unroll
  for (int c = 0; c < Cc; ++c) { fgs[c] = f[c] - lse; accv[c] = bb2; }
  for (int h = 0; h < Hh; ++h) {
    float w0 = W1[2 * h], w1 = W1[2 * h + 1], bb = b1[h], w2 = W2[h];
#pragma unroll
    for (int c = 0; c < Cc; ++c)
      accv[c] += w2 * fmaxf(fgs[c] * w0 + pm[c] * w1 + bb, 0.f);
  }
#pragma unroll
  for (int c = 0; c < Cc; ++c) out[m * Cc + c] = accv[c];
}

// ---------------------------------------------------------------------------
extern "C" void kernel_launch(void* const* d_in, const int* in_sizes, int n_in,
                              void* d_out, int out_size, void* d_ws, size_t ws_size,
                              hipStream_t stream) {
  const float* ctxt_vec = (const float*)d_in[1];   // [M][W][D]
  const float* cand_vec = (const float*)d_in[3];   // [M][C][D]
  const float* pem      = (const float*)d_in[4];   // [M][C]
  const float* A        = (const float*)d_in[5];
  const float* B        = (const float*)d_in[6];
  const float* Cl       = (const float*)d_in[7];
  const float* W1       = (const float*)d_in[8];
  const float* b1       = (const float*)d_in[9];
  const float* W2       = (const float*)d_in[10];
  const float* b2       = (const float*)d_in[11];
  float* out = (float*)d_out;

  char* ws = (char*)d_ws;
  _Float16* P     = (_Float16*)(ws);                      // 20,480,000 B
  float*   msg    = (float*)(ws + 20480000);              //  5,120,000 B
  // Ah/Bh alias the msg region (live only until GEMM; memset is after GEMM)
  _Float16* Ah    = (_Float16*)(ws + 20480000);           //  2,048,000 B
  _Float16* Bh    = (_Float16*)(ws + 20480000 + 2048000); //  2,048,000 B
  float*   scores = (float*)(ws + 25600000);
  float*   col0   = scores + MC;
  float*   col1   = col0 + MC;

  k_convert<<<(MC * KP + 255) / 256, 256, 0, stream>>>(cand_vec, Cl, Ah, Bh);
  k_entity_context<<<Mm, 256, 0, stream>>>(ctxt_vec, cand_vec, A, B, scores, col0);

  dim3 g(MC / 128, MC / 128);
  k_pairwise_mfma<<<g, 256, 0, stream>>>(Ah, Bh, P);

  hipMemsetAsync(msg, 0, (size_t)MC * Mm * sizeof(float), stream);  // after GEMM (alias!)

  float* cIn = col0; float* cOut = col1;
  for (int it = 0; it < LBP_ITERS; ++it) {
    k_lbp<<<Mm, 256, 0, stream>>>(P, cIn, scores, msg, cOut);
    float* t = cIn; cIn = cOut; cOut = t;
  }
  k_final2<<<(Mm + 63) / 64, 64, 0, stream>>>(cIn, pem, W1, b1, W2, b2, out);
}